// Round 1
// baseline (46.100 us; speedup 1.0000x reference)
//
#include <hip/hip_runtime.h>
#include <hip/hip_bf16.h>

#define NG 128
#define NT 16
#define NB 4

// ws float layout:
//   gtab  [128][8] : {betaT0..3, phi, phi*log(phi), 0, 0}
//   mdemd [128][16][2] : {md, exp(md)}
//   lgtab [128][20] : gammaln(phi+k) - gammaln(1+k) - gammaln(phi)
#define GTAB_OFF 0
#define MDEMD_OFF 1024
#define LGTAB_OFF 5120

__global__ void setup_kernel(const float* __restrict__ delta,
                             const float* __restrict__ beta,
                             const float* __restrict__ phi,
                             const float* __restrict__ mo,
                             float* __restrict__ ws,
                             float* __restrict__ out) {
    int g = threadIdx.x;
    if (g == 0) out[0] = 0.0f;   // deterministic re-init every call
    if (g >= NG) return;
    float* gtab  = ws + GTAB_OFF;
    float* mdemd = ws + MDEMD_OFF;
    float* lgtab = ws + LGTAB_OFF;

    float ph = phi[g];
    ph = fminf(fmaxf(ph, 1.0f), 100.0f);
    float lphi = logf(ph);
    gtab[g * 8 + 0] = beta[0 * NG + g];
    gtab[g * 8 + 1] = beta[1 * NG + g];
    gtab[g * 8 + 2] = beta[2 * NG + g];
    gtab[g * 8 + 3] = beta[3 * NG + g];
    gtab[g * 8 + 4] = ph;
    gtab[g * 8 + 5] = ph * lphi;
    gtab[g * 8 + 6] = 0.0f;
    gtab[g * 8 + 7] = 0.0f;

    for (int t = 0; t < NT; ++t) {
        float md = mo[g * NT + t] * delta[g * NT + t];
        mdemd[g * 32 + t * 2 + 0] = md;
        mdemd[g * 32 + t * 2 + 1] = expf(md);
    }

    // lgtab[k] = sum_{j=0}^{k-1} log(phi+j) - log(k!)
    double accn = 0.0, lf = 0.0;
    lgtab[g * 20 + 0] = 0.0f;
    for (int k = 1; k < 20; ++k) {
        accn += log((double)ph + (double)(k - 1));
        if (k >= 2) lf += log((double)k);
        lgtab[g * 20 + k] = (float)(accn - lf);
    }
}

__global__ __launch_bounds__(256) void nb_kernel(const float* __restrict__ expr,
                                                 const float* __restrict__ cov,
                                                 const float* __restrict__ sfv,
                                                 const float* __restrict__ ws,
                                                 float* __restrict__ out,
                                                 int ns) {
    const float* __restrict__ gtab  = ws + GTAB_OFF;
    const float* __restrict__ mdemd = ws + MDEMD_OFF;
    const float* __restrict__ lgtab = ws + LGTAB_OFF;

    const int lane = threadIdx.x & 63;
    const int q = __builtin_amdgcn_readfirstlane(threadIdx.x >> 6);  // wave-uniform quarter
    const int s = blockIdx.x * 64 + lane;
    const bool valid = (s < ns);

    float acc[NT];
#pragma unroll
    for (int t = 0; t < NT; ++t) acc[t] = 0.0f;

    float4 cv = make_float4(0.f, 0.f, 0.f, 0.f);
    float sf = 1.0f;
    if (valid) {
        cv = *reinterpret_cast<const float4*>(cov + (size_t)s * 4);
        sf = sfv[s];
    }
    const float lsf = __logf(sf);
    const int g0 = q * 32;

    for (int gg4 = 0; gg4 < 8; ++gg4) {
        float4 kv = make_float4(0.f, 0.f, 0.f, 0.f);
        if (valid)
            kv = *reinterpret_cast<const float4*>(expr + (size_t)s * NG + g0 + gg4 * 4);
        float kfv[4] = {kv.x, kv.y, kv.z, kv.w};
#pragma unroll
        for (int j = 0; j < 4; ++j) {
            const int g = g0 + gg4 * 4 + j;
            const float b0 = gtab[g * 8 + 0];
            const float b1 = gtab[g * 8 + 1];
            const float b2 = gtab[g * 8 + 2];
            const float b3 = gtab[g * 8 + 3];
            const float ph  = gtab[g * 8 + 4];
            const float plp = gtab[g * 8 + 5];

            float e = fmaf(b3, cv.w, fmaf(b2, cv.z, fmaf(b1, cv.y, b0 * cv.x)));
            float c = sf * __expf(e);
            float kf = kfv[j];
            int ki = (int)kf;
            float lg = lgtab[g * 20 + ki];           // per-lane (k varies), L1-resident
            float h = fmaf(kf, lsf + e, lg + plp);
            float nkp2 = -(kf + ph) * 0.6931471805599453f;  // fold ln2 into coeff
#pragma unroll
            for (int t = 0; t < NT; ++t) {
                float md  = mdemd[g * 32 + t * 2 + 0];
                float emd = mdemd[g * 32 + t * 2 + 1];
                float v = fmaf(c, emd, ph);          // mu + phi
                float l2 = __log2f(v);
                acc[t] = fmaf(nkp2, l2, acc[t] + fmaf(kf, md, h));
            }
        }
    }

    __shared__ float part[4][64][17];
#pragma unroll
    for (int t = 0; t < NT; ++t) part[q][lane][t] = acc[t];
    __syncthreads();

    if (threadIdx.x < 64) {
        float tot[NT];
#pragma unroll
        for (int t = 0; t < NT; ++t)
            tot[t] = part[0][lane][t] + part[1][lane][t] + part[2][lane][t] + part[3][lane][t];
        float m = tot[0];
#pragma unroll
        for (int t = 1; t < NT; ++t) m = fmaxf(m, tot[t]);
        float sum = 0.0f;
#pragma unroll
        for (int t = 0; t < NT; ++t) sum += __expf(tot[t] - m);
        float lp = m + __logf(sum);
        if (!valid) lp = 0.0f;
#pragma unroll
        for (int off = 32; off > 0; off >>= 1) lp += __shfl_down(lp, off);
        if (lane == 0) atomicAdd(out, lp);
    }
}

extern "C" void kernel_launch(void* const* d_in, const int* in_sizes, int n_in,
                              void* d_out, int out_size, void* d_ws, size_t ws_size,
                              hipStream_t stream) {
    const float* delta = (const float*)d_in[0];
    const float* beta  = (const float*)d_in[1];
    const float* phi   = (const float*)d_in[2];
    const float* expr  = (const float*)d_in[3];
    const float* cov   = (const float*)d_in[4];
    const float* sf    = (const float*)d_in[5];
    const float* mo    = (const float*)d_in[6];
    float* out = (float*)d_out;
    float* ws  = (float*)d_ws;
    const int ns = in_sizes[5];

    setup_kernel<<<1, 128, 0, stream>>>(delta, beta, phi, mo, ws, out);
    const int blocks = (ns + 63) / 64;
    nb_kernel<<<blocks, 256, 0, stream>>>(expr, cov, sf, ws, out, ns);
}

// Round 2
// 39.837 us; speedup vs baseline: 1.1572x; 1.1572x over previous
//
#include <hip/hip_runtime.h>
#include <hip/hip_bf16.h>

#define NG 128
#define NT 16

// ws float layout:
//   gtab  [128][8]  : {betaT0..3, phi, phi*log(phi), 0, 0}          (1024 f)
//   mdemd [128][16][2] : {md, exp(md)} interleaved                  (4096 f)
//   lgtab [128][20] : gammaln(phi+k)-gammaln(1+k)-gammaln(phi)      (2560 f)
//   part  [4][nsp][16] : per-quarter partial type-sums
#define GTAB_OFF 0
#define MDEMD_OFF 1024
#define LGTAB_OFF 5120
#define PART_OFF 8192
#define LN2 0.6931471805599453f

__global__ void setup_kernel(const float* __restrict__ delta,
                             const float* __restrict__ beta,
                             const float* __restrict__ phi,
                             const float* __restrict__ mo,
                             float* __restrict__ ws,
                             float* __restrict__ out) {
    int g = threadIdx.x;
    if (g == 0) out[0] = 0.0f;   // deterministic re-init every call
    if (g >= NG) return;
    float* gtab  = ws + GTAB_OFF;
    float* mdemd = ws + MDEMD_OFF;
    float* lgtab = ws + LGTAB_OFF;

    float ph = phi[g];
    ph = fminf(fmaxf(ph, 1.0f), 100.0f);
    float lphi = logf(ph);
    gtab[g * 8 + 0] = beta[0 * NG + g];
    gtab[g * 8 + 1] = beta[1 * NG + g];
    gtab[g * 8 + 2] = beta[2 * NG + g];
    gtab[g * 8 + 3] = beta[3 * NG + g];
    gtab[g * 8 + 4] = ph;
    gtab[g * 8 + 5] = ph * lphi;
    gtab[g * 8 + 6] = 0.0f;
    gtab[g * 8 + 7] = 0.0f;

    for (int t = 0; t < NT; ++t) {
        float md = mo[g * NT + t] * delta[g * NT + t];
        mdemd[g * 32 + t * 2 + 0] = md;
        mdemd[g * 32 + t * 2 + 1] = expf(md);
    }

    double accn = 0.0, lf = 0.0;
    lgtab[g * 20 + 0] = 0.0f;
    for (int k = 1; k < 20; ++k) {
        accn += log((double)ph + (double)(k - 1));
        if (k >= 2) lf += log((double)k);
        lgtab[g * 20 + k] = (float)(accn - lf);
    }
}

// Phase 1: each block = 64 samples x 32 genes (one quarter). 4 waves, 8 genes each.
__global__ __launch_bounds__(256) void nb_phase1(const float* __restrict__ expr,
                                                 const float* __restrict__ cov,
                                                 const float* __restrict__ sfv,
                                                 const float* __restrict__ ws,
                                                 float* __restrict__ part_out,
                                                 int ns, int nsp) {
    __shared__ float s_gt[256];
    __shared__ float s_md[1024];
    __shared__ float s_lg[640];
    __shared__ float part[4][64][17];

    const int tid = threadIdx.x;
    const int tile = blockIdx.x >> 2;
    const int quarter = blockIdx.x & 3;

    // cooperative table staging (all float4-aligned)
    *(float4*)&s_md[tid * 4] = *(const float4*)(ws + MDEMD_OFF + quarter * 1024 + tid * 4);
    if (tid < 64)  *(float4*)&s_gt[tid * 4] = *(const float4*)(ws + GTAB_OFF  + quarter * 256 + tid * 4);
    if (tid < 160) *(float4*)&s_lg[tid * 4] = *(const float4*)(ws + LGTAB_OFF + quarter * 640 + tid * 4);
    __syncthreads();

    const int lane = tid & 63;
    const int q = __builtin_amdgcn_readfirstlane(tid >> 6);
    const int s = tile * 64 + lane;
    const bool valid = (s < ns);

    float acc[NT];
#pragma unroll
    for (int t = 0; t < NT; ++t) acc[t] = 0.0f;
    float hacc = 0.0f;

    float4 cv = make_float4(0.f, 0.f, 0.f, 0.f);
    float sf = 1.0f;
    if (valid) {
        cv = *reinterpret_cast<const float4*>(cov + (size_t)s * 4);
        sf = sfv[s];
    }
    const float lsf = __logf(sf);

    const int glb = q * 8;  // local gene base within quarter
    float kbuf[8] = {0, 0, 0, 0, 0, 0, 0, 0};
    if (valid) {
        float4 k0 = *reinterpret_cast<const float4*>(expr + (size_t)s * NG + quarter * 32 + glb);
        float4 k1 = *reinterpret_cast<const float4*>(expr + (size_t)s * NG + quarter * 32 + glb + 4);
        kbuf[0] = k0.x; kbuf[1] = k0.y; kbuf[2] = k0.z; kbuf[3] = k0.w;
        kbuf[4] = k1.x; kbuf[5] = k1.y; kbuf[6] = k1.z; kbuf[7] = k1.w;
    }

#pragma unroll
    for (int jj = 0; jj < 8; ++jj) {
        const int gl = glb + jj;
        const float b0 = s_gt[gl * 8 + 0];
        const float b1 = s_gt[gl * 8 + 1];
        const float b2 = s_gt[gl * 8 + 2];
        const float b3 = s_gt[gl * 8 + 3];
        const float ph  = s_gt[gl * 8 + 4];
        const float plp = s_gt[gl * 8 + 5];

        float e = fmaf(b3, cv.w, fmaf(b2, cv.z, fmaf(b1, cv.y, b0 * cv.x)));
        float c = sf * __expf(e);
        float kf = kbuf[jj];
        int ki = (int)kf;
        float lg = s_lg[gl * 20 + ki];
        hacc += fmaf(kf, lsf + e, lg + plp);      // type-independent term, hoisted
        float nkp2 = -(kf + ph) * LN2;
#pragma unroll
        for (int t = 0; t < NT; ++t) {
            float md  = s_md[gl * 32 + 2 * t];
            float emd = s_md[gl * 32 + 2 * t + 1];
            float v = fmaf(c, emd, ph);           // mu + phi
            acc[t] = fmaf(nkp2, __log2f(v), fmaf(kf, md, acc[t]));
        }
    }
#pragma unroll
    for (int t = 0; t < NT; ++t) acc[t] += hacc;

#pragma unroll
    for (int t = 0; t < NT; ++t) part[q][lane][t] = acc[t];
    __syncthreads();

    // each wave writes 4 of the 16 types, float4-coalesced
    const int t0 = q * 4;
    float4 o;
    o.x = part[0][lane][t0 + 0] + part[1][lane][t0 + 0] + part[2][lane][t0 + 0] + part[3][lane][t0 + 0];
    o.y = part[0][lane][t0 + 1] + part[1][lane][t0 + 1] + part[2][lane][t0 + 1] + part[3][lane][t0 + 1];
    o.z = part[0][lane][t0 + 2] + part[1][lane][t0 + 2] + part[2][lane][t0 + 2] + part[3][lane][t0 + 2];
    o.w = part[0][lane][t0 + 3] + part[1][lane][t0 + 3] + part[2][lane][t0 + 3] + part[3][lane][t0 + 3];
    *reinterpret_cast<float4*>(part_out + ((size_t)quarter * nsp + (size_t)tile * 64 + lane) * 16 + t0) = o;
}

// Phase 2: per-sample combine of 4 quarter-partials + logsumexp + grand sum
__global__ __launch_bounds__(256) void nb_phase2(const float* __restrict__ part_in,
                                                 float* __restrict__ out,
                                                 int ns, int nsp) {
    const int s = blockIdx.x * 256 + threadIdx.x;
    float lp = 0.0f;
    if (s < ns) {
        float tot[NT];
#pragma unroll
        for (int t = 0; t < NT; ++t) tot[t] = 0.0f;
#pragma unroll
        for (int qt = 0; qt < 4; ++qt) {
            const float* base = part_in + ((size_t)qt * nsp + s) * 16;
#pragma unroll
            for (int v4 = 0; v4 < 4; ++v4) {
                float4 p = *reinterpret_cast<const float4*>(base + v4 * 4);
                tot[v4 * 4 + 0] += p.x;
                tot[v4 * 4 + 1] += p.y;
                tot[v4 * 4 + 2] += p.z;
                tot[v4 * 4 + 3] += p.w;
            }
        }
        float m = tot[0];
#pragma unroll
        for (int t = 1; t < NT; ++t) m = fmaxf(m, tot[t]);
        float sum = 0.0f;
#pragma unroll
        for (int t = 0; t < NT; ++t) sum += __expf(tot[t] - m);
        lp = m + __logf(sum);
    }
#pragma unroll
    for (int off = 32; off > 0; off >>= 1) lp += __shfl_down(lp, off);
    __shared__ float r[4];
    if ((threadIdx.x & 63) == 0) r[threadIdx.x >> 6] = lp;
    __syncthreads();
    if (threadIdx.x == 0) atomicAdd(out, r[0] + r[1] + r[2] + r[3]);
}

// Fallback (proven round-1 single-phase kernel) if ws is too small for partials
__global__ __launch_bounds__(256) void nb_single(const float* __restrict__ expr,
                                                 const float* __restrict__ cov,
                                                 const float* __restrict__ sfv,
                                                 const float* __restrict__ ws,
                                                 float* __restrict__ out,
                                                 int ns) {
    const float* __restrict__ gtab  = ws + GTAB_OFF;
    const float* __restrict__ mdemd = ws + MDEMD_OFF;
    const float* __restrict__ lgtab = ws + LGTAB_OFF;

    const int lane = threadIdx.x & 63;
    const int q = __builtin_amdgcn_readfirstlane(threadIdx.x >> 6);
    const int s = blockIdx.x * 64 + lane;
    const bool valid = (s < ns);

    float acc[NT];
#pragma unroll
    for (int t = 0; t < NT; ++t) acc[t] = 0.0f;
    float hacc = 0.0f;

    float4 cv = make_float4(0.f, 0.f, 0.f, 0.f);
    float sf = 1.0f;
    if (valid) {
        cv = *reinterpret_cast<const float4*>(cov + (size_t)s * 4);
        sf = sfv[s];
    }
    const float lsf = __logf(sf);
    const int g0 = q * 32;

    for (int gg4 = 0; gg4 < 8; ++gg4) {
        float4 kv = make_float4(0.f, 0.f, 0.f, 0.f);
        if (valid)
            kv = *reinterpret_cast<const float4*>(expr + (size_t)s * NG + g0 + gg4 * 4);
        float kfv[4] = {kv.x, kv.y, kv.z, kv.w};
#pragma unroll
        for (int j = 0; j < 4; ++j) {
            const int g = g0 + gg4 * 4 + j;
            const float b0 = gtab[g * 8 + 0];
            const float b1 = gtab[g * 8 + 1];
            const float b2 = gtab[g * 8 + 2];
            const float b3 = gtab[g * 8 + 3];
            const float ph  = gtab[g * 8 + 4];
            const float plp = gtab[g * 8 + 5];

            float e = fmaf(b3, cv.w, fmaf(b2, cv.z, fmaf(b1, cv.y, b0 * cv.x)));
            float c = sf * __expf(e);
            float kf = kfv[j];
            int ki = (int)kf;
            float lg = lgtab[g * 20 + ki];
            hacc += fmaf(kf, lsf + e, lg + plp);
            float nkp2 = -(kf + ph) * LN2;
#pragma unroll
            for (int t = 0; t < NT; ++t) {
                float md  = mdemd[g * 32 + t * 2 + 0];
                float emd = mdemd[g * 32 + t * 2 + 1];
                float v = fmaf(c, emd, ph);
                acc[t] = fmaf(nkp2, __log2f(v), fmaf(kf, md, acc[t]));
            }
        }
    }
#pragma unroll
    for (int t = 0; t < NT; ++t) acc[t] += hacc;

    __shared__ float part[4][64][17];
#pragma unroll
    for (int t = 0; t < NT; ++t) part[q][lane][t] = acc[t];
    __syncthreads();

    if (threadIdx.x < 64) {
        float tot[NT];
#pragma unroll
        for (int t = 0; t < NT; ++t)
            tot[t] = part[0][lane][t] + part[1][lane][t] + part[2][lane][t] + part[3][lane][t];
        float m = tot[0];
#pragma unroll
        for (int t = 1; t < NT; ++t) m = fmaxf(m, tot[t]);
        float sum = 0.0f;
#pragma unroll
        for (int t = 0; t < NT; ++t) sum += __expf(tot[t] - m);
        float lp = m + __logf(sum);
        if (!valid) lp = 0.0f;
#pragma unroll
        for (int off = 32; off > 0; off >>= 1) lp += __shfl_down(lp, off);
        if (lane == 0) atomicAdd(out, lp);
    }
}

extern "C" void kernel_launch(void* const* d_in, const int* in_sizes, int n_in,
                              void* d_out, int out_size, void* d_ws, size_t ws_size,
                              hipStream_t stream) {
    const float* delta = (const float*)d_in[0];
    const float* beta  = (const float*)d_in[1];
    const float* phi   = (const float*)d_in[2];
    const float* expr  = (const float*)d_in[3];
    const float* cov   = (const float*)d_in[4];
    const float* sf    = (const float*)d_in[5];
    const float* mo    = (const float*)d_in[6];
    float* out = (float*)d_out;
    float* ws  = (float*)d_ws;
    const int ns = in_sizes[5];

    setup_kernel<<<1, 128, 0, stream>>>(delta, beta, phi, mo, ws, out);

    const int tiles = (ns + 63) / 64;
    const int nsp = tiles * 64;
    const size_t need = ((size_t)PART_OFF + 4ull * (size_t)nsp * 16ull) * 4ull;

    if (ws_size >= need) {
        float* part = ws + PART_OFF;
        nb_phase1<<<tiles * 4, 256, 0, stream>>>(expr, cov, sf, ws, part, ns, nsp);
        nb_phase2<<<(ns + 255) / 256, 256, 0, stream>>>(part, out, ns, nsp);
    } else {
        nb_single<<<tiles, 256, 0, stream>>>(expr, cov, sf, ws, out, ns);
    }
}